// Round 1
// baseline (510.989 us; speedup 1.0000x reference)
//
#include <hip/hip_runtime.h>
#include <hip/hip_bf16.h>
#include <cstdint>
#include <cstddef>

// Problem dims (fixed by reference)
#define BDIM 512
#define SDIM 64
#define DDIM 256
#define D2   512
#define NNODE 100000
#define NM1  99999   // logits columns

typedef short short8 __attribute__((ext_vector_type(8)));
typedef float f32x4 __attribute__((ext_vector_type(4)));

__device__ __forceinline__ unsigned short f2bf(float f) {
  unsigned int u = __float_as_uint(f);
  u += 0x7FFFu + ((u >> 16) & 1u);   // RNE
  return (unsigned short)(u >> 16);
}

// ---------------------------------------------------------------------------
// Kernel 1: per-batch prep. Only row s* = alias[b, rm-1] of the batched
// matmuls is ever used downstream, so compute just that row.
// av[b, 0:256] = adj_in[b,s*,:] @ emb[item[b,:]]; av[b,256:512] = adj_out row.
// ---------------------------------------------------------------------------
__global__ __launch_bounds__(256) void prep_kernel(
    const float* __restrict__ emb, const float* __restrict__ adj_in,
    const float* __restrict__ adj_out, const float* __restrict__ mask,
    const int* __restrict__ item, const int* __restrict__ alias_,
    float* __restrict__ av) {
  __shared__ float a_in[SDIM], a_out[SDIM];
  __shared__ int it[SDIM];
  __shared__ int s_star;
  const int b = blockIdx.x, t = threadIdx.x;
  if (t < SDIM) it[t] = item[b * SDIM + t];
  if (t == 0) {
    float s = 0.f;
    for (int j = 0; j < SDIM; j++) s += mask[b * SDIM + j];
    int rm = (int)s;                       // matches astype(int32) truncation
    s_star = alias_[b * SDIM + rm - 1];
  }
  __syncthreads();
  const int ss = s_star;
  if (t < SDIM) a_in[t] = adj_in[((size_t)b * SDIM + ss) * SDIM + t];
  else if (t < 2 * SDIM) a_out[t - SDIM] = adj_out[((size_t)b * SDIM + ss) * SDIM + (t - SDIM)];
  __syncthreads();
  const int d = t;  // 256 threads == DDIM
  float ai = 0.f, ao = 0.f;
#pragma unroll 8
  for (int j = 0; j < SDIM; j++) {
    float e = emb[(size_t)it[j] * DDIM + d];  // coalesced across d
    ai = fmaf(a_in[j], e, ai);
    ao = fmaf(a_out[j], e, ao);
  }
  av[(size_t)b * D2 + d] = ai;
  av[(size_t)b * D2 + DDIM + d] = ao;
}

// ---------------------------------------------------------------------------
// Kernel 2: h1[512,512] = relu(av[512,512] @ W1[512,512])  (fp32, tiny GEMM)
// ---------------------------------------------------------------------------
__global__ __launch_bounds__(256) void mlp1_kernel(
    const float* __restrict__ A, const float* __restrict__ W,
    float* __restrict__ O) {
  __shared__ float As[16][16];
  __shared__ float Bs[16][17];
  const int tx = threadIdx.x, ty = threadIdx.y;
  const int row = blockIdx.y * 16 + ty, col = blockIdx.x * 16 + tx;
  float acc = 0.f;
  for (int k0 = 0; k0 < D2; k0 += 16) {
    As[ty][tx] = A[(size_t)row * D2 + k0 + tx];
    Bs[ty][tx] = W[(size_t)(k0 + ty) * D2 + col];
    __syncthreads();
#pragma unroll
    for (int k = 0; k < 16; k++) acc = fmaf(As[ty][k], Bs[k][tx], acc);
    __syncthreads();
  }
  O[(size_t)row * D2 + col] = fmaxf(acc, 0.f);
}

// ---------------------------------------------------------------------------
// Kernel 3: last_h(bf16)[512,256] = h1[512,512] @ W2[512,256]
// ---------------------------------------------------------------------------
__global__ __launch_bounds__(256) void mlp2_kernel(
    const float* __restrict__ A, const float* __restrict__ W,
    unsigned short* __restrict__ O) {
  __shared__ float As[16][16];
  __shared__ float Bs[16][17];
  const int tx = threadIdx.x, ty = threadIdx.y;
  const int row = blockIdx.y * 16 + ty, col = blockIdx.x * 16 + tx;
  float acc = 0.f;
  for (int k0 = 0; k0 < D2; k0 += 16) {
    As[ty][tx] = A[(size_t)row * D2 + k0 + tx];
    Bs[ty][tx] = W[(size_t)(k0 + ty) * DDIM + col];
    __syncthreads();
#pragma unroll
    for (int k = 0; k < 16; k++) acc = fmaf(As[ty][k], Bs[k][tx], acc);
    __syncthreads();
  }
  O[(size_t)row * DDIM + col] = f2bf(acc);
}

// ---------------------------------------------------------------------------
// Kernel 4: logits[512, 99999] = last_h(bf16) @ emb[1:]^T  (bf16 MFMA)
// Fused epilogue: per-row sum of exp(logit) -> atomicAdd into rse[512].
// Tile 128x128, BK=64, 4 waves (2x2), each wave 4x4 frags of 16x16x32.
// LDS stride 72 shorts: 16B-aligned, <=2-way bank aliasing (free per m136).
// ---------------------------------------------------------------------------
#define LDA 72
__global__ __launch_bounds__(256) void logits_gemm(
    const unsigned short* __restrict__ Abf,  // [512,256] bf16
    const float* __restrict__ emb,           // [100000,256] f32
    float* __restrict__ out,                 // d_out: [0]=loss, [1..]=logits
    float* __restrict__ rse) {               // [512] running sum-exp
  __shared__ short As[128 * LDA];
  __shared__ short Bs[128 * LDA];
  const int t = threadIdx.x;
  const int mbase = blockIdx.x * 128;   // 4 m-tiles (fast index: B-tile shared)
  const int nbase = blockIdx.y * 128;   // 782 n-tiles
  const int lane = t & 63, w = t >> 6;
  const int wm = (w >> 1) * 64, wn = (w & 1) * 64;
  const int c = lane & 15, q = lane >> 4;

  f32x4 acc[4][4];
#pragma unroll
  for (int mi = 0; mi < 4; mi++)
#pragma unroll
    for (int ni = 0; ni < 4; ni++) acc[mi][ni] = (f32x4){0.f, 0.f, 0.f, 0.f};

  const int r8 = t >> 3;         // staging row group 0..31
  const int kcol = (t & 7) * 8;  // 8-elem k segment

  for (int k0 = 0; k0 < DDIM; k0 += 64) {
    __syncthreads();
#pragma unroll
    for (int i = 0; i < 4; i++) {
      const int row = i * 32 + r8;  // 0..127
      // A tile: bf16, 16B vector load
      const short8 a8 = *(const short8*)(Abf + (size_t)(mbase + row) * DDIM + k0 + kcol);
      *(short8*)&As[row * LDA + kcol] = a8;
      // B tile: emb row n+1 (f32) -> bf16 inline
      const int n = nbase + row;
      const int er = (n + 1 <= NM1) ? (n + 1) : NM1;  // clamp; invalid cols masked later
      const float* bg = emb + (size_t)er * DDIM + k0 + kcol;
      const float4 b0 = *(const float4*)bg;
      const float4 b1 = *(const float4*)(bg + 4);
      short8 p;
      p[0] = (short)f2bf(b0.x); p[1] = (short)f2bf(b0.y);
      p[2] = (short)f2bf(b0.z); p[3] = (short)f2bf(b0.w);
      p[4] = (short)f2bf(b1.x); p[5] = (short)f2bf(b1.y);
      p[6] = (short)f2bf(b1.z); p[7] = (short)f2bf(b1.w);
      *(short8*)&Bs[row * LDA + kcol] = p;
    }
    __syncthreads();
#pragma unroll
    for (int kk = 0; kk < 64; kk += 32) {
      short8 afr[4], bfr[4];
#pragma unroll
      for (int mi = 0; mi < 4; mi++)
        afr[mi] = *(const short8*)&As[(wm + mi * 16 + c) * LDA + kk + q * 8];
#pragma unroll
      for (int ni = 0; ni < 4; ni++)
        bfr[ni] = *(const short8*)&Bs[(wn + ni * 16 + c) * LDA + kk + q * 8];
#pragma unroll
      for (int mi = 0; mi < 4; mi++)
#pragma unroll
        for (int ni = 0; ni < 4; ni++)
          acc[mi][ni] = __builtin_amdgcn_mfma_f32_16x16x32_bf16(
              afr[mi], bfr[ni], acc[mi][ni], 0, 0, 0);
    }
  }

  // Epilogue: store logits (scalar f32 — base d_out+1 is 4B-misaligned for
  // vec4) + per-row partial sum of exp, reduced over the 16 col-lanes.
#pragma unroll
  for (int mi = 0; mi < 4; mi++) {
#pragma unroll
    for (int r = 0; r < 4; r++) {
      const int grow = mbase + wm + mi * 16 + q * 4 + r;  // C/D: row=q*4+reg
      float s = 0.f;
#pragma unroll
      for (int ni = 0; ni < 4; ni++) {
        const int col = nbase + wn + ni * 16 + c;         // C/D: col=lane&15
        if (col < NM1) {
          const float v = acc[mi][ni][r];
          out[1 + (size_t)grow * NM1 + col] = v;
          s += __expf(v);
        }
      }
#pragma unroll
      for (int msk = 1; msk < 16; msk <<= 1) s += __shfl_xor(s, msk, 64);
      if (c == 0) atomicAdd(&rse[grow], s);
    }
  }
}

// ---------------------------------------------------------------------------
// Kernel 5: loss = mean_b( log(sum_exp[b]) - logits[b, tar[b]-1] )
// ---------------------------------------------------------------------------
__global__ __launch_bounds__(512) void loss_kernel(
    float* __restrict__ out, const float* __restrict__ rse,
    const int* __restrict__ tar) {
  __shared__ float red[512];
  const int t = threadIdx.x;
  const int tt = tar[t];
  const float lg = out[1 + (size_t)t * NM1 + (tt - 1)];
  red[t] = logf(rse[t]) - lg;
  __syncthreads();
  for (int stride = 256; stride > 0; stride >>= 1) {
    if (t < stride) red[t] += red[t + stride];
    __syncthreads();
  }
  if (t == 0) out[0] = red[0] / (float)BDIM;
}

// ---------------------------------------------------------------------------
extern "C" void kernel_launch(void* const* d_in, const int* in_sizes, int n_in,
                              void* d_out, int out_size, void* d_ws, size_t ws_size,
                              hipStream_t stream) {
  const float* emb     = (const float*)d_in[0];
  const float* W1      = (const float*)d_in[1];
  const float* W2      = (const float*)d_in[2];
  const float* adj_in  = (const float*)d_in[3];
  const float* adj_out = (const float*)d_in[4];
  const float* mask    = (const float*)d_in[5];
  const int*   item    = (const int*)d_in[6];
  const int*   alias_  = (const int*)d_in[7];
  const int*   tar     = (const int*)d_in[8];
  float* out = (float*)d_out;

  char* ws = (char*)d_ws;
  float* av            = (float*)(ws);                 // 512*512*4 = 1 MB
  float* h1            = (float*)(ws + 1048576);       // 512*512*4 = 1 MB
  unsigned short* lasth = (unsigned short*)(ws + 2097152); // 512*256*2 = 256 KB
  float* rse           = (float*)(ws + 2359296);       // 512*4

  hipMemsetAsync(rse, 0, BDIM * sizeof(float), stream);
  prep_kernel<<<BDIM, 256, 0, stream>>>(emb, adj_in, adj_out, mask, item, alias_, av);
  mlp1_kernel<<<dim3(32, 32), dim3(16, 16), 0, stream>>>(av, W1, h1);
  mlp2_kernel<<<dim3(16, 32), dim3(16, 16), 0, stream>>>(h1, W2, lasth);
  logits_gemm<<<dim3(4, 782), 256, 0, stream>>>(lasth, emb, out, rse);
  loss_kernel<<<1, 512, 0, stream>>>(out, rse, tar);
}